// Round 5
// baseline (6491.872 us; speedup 1.0000x reference)
//
#include <hip/hip_runtime.h>

// ============================================================================
// BiLSTM + CRF Viterbi.  Round 5:
//  - lstm_persist v2: 4mh x 2nn wave layout over full K (no k-half reduce),
//    4-buffer LDS chunk ping-pong (1 sync / 2 chunks), padded W/gex LDS rows
//    (kills 8-way bank conflicts), arrival-array barrier (no RMW serialize,
//    wave-parallel poll), xp prefetch, masks -> (t < length[b]).
//  - viterbi v2: stage emission row (48KB) + transitions in LDS; tcol in regs.
//  - xp_gemm / emis / splits unchanged.
// ============================================================================

#define B_ 64
#define T_ 512
#define NT_ 24

typedef __attribute__((ext_vector_type(8))) short bf16x8;
typedef __attribute__((ext_vector_type(4))) float f32x4;

#define MFMA16(a, b, c) __builtin_amdgcn_mfma_f32_16x16x32_bf16(a, b, c, 0, 0, 0)

__device__ __forceinline__ unsigned short f2bf(float x) {
  unsigned u = __float_as_uint(x);
  u += 0x7FFFu + ((u >> 16) & 1u);  // round-to-nearest-even
  return (unsigned short)(u >> 16);
}
__device__ __forceinline__ float bf2f(unsigned short h) {
  return __uint_as_float(((unsigned)h) << 16);
}

// ---------------- ws layout (bytes) ----------------
#define SZ_WPL  ((size_t)8388608)                 // [dir][pl][2048][512] u16
#define O_WHH   ((size_t)0)
#define O_WIH   (O_WHH + SZ_WPL)
#define O_XSPL  (O_WIH + SZ_WPL)                  // X hi/lo planes
#define SZ_XSPL ((size_t)67108864)
#define O_OUTPL (O_XSPL + SZ_XSPL)                // [dir][pl][b][t][h]
#define SZ_OUTPL ((size_t)134217728)
#define O_HBUF  (O_OUTPL + SZ_OUTPL)              // [dir][buf][64][512] u32 packed
#define SZ_HBUF ((size_t)524288)
#define O_HF32  (O_HBUF + SZ_HBUF)
#define SZ_ST   ((size_t)262144)                  // [dir][64][512] f32
#define O_CF32  (O_HF32 + SZ_ST)
#define O_EMIS  (O_CF32 + SZ_ST)
#define SZ_EMIS ((size_t)3145728)                 // [64][512][24] f32
#define O_BAR   (O_EMIS + SZ_EMIS)                // 512 B arrival array
#define O_XP    (O_BAR + 512)                     // + Tc MiB ([2][Tc][64][2048] f32)

// ---------------- fp32 -> bf16 hi/lo split ----------------
__global__ void split_kernel(const float* __restrict__ src,
                             unsigned short* __restrict__ hi,
                             unsigned short* __restrict__ lo, int n) {
  int i = blockIdx.x * blockDim.x + threadIdx.x;
  int stride = gridDim.x * blockDim.x;
  for (; i < n; i += stride) {
    float x = src[i];
    unsigned short h = f2bf(x);
    hi[i] = h;
    lo[i] = f2bf(x - bf2f(h));
  }
}

// ---------------- xp GEMM (unchanged) ----------------
__global__ __launch_bounds__(256) void xp_gemm(
    const unsigned short* __restrict__ xpl,     // [pl][16777216]
    const unsigned short* __restrict__ wih_pl,  // [dir][pl][1048576]
    const float* __restrict__ bias_f, const float* __restrict__ bias_b,
    const int* __restrict__ length,
    float* __restrict__ xp, int t0, int Tc) {
  __shared__ char smem[65536];   // Ahi|Alo|Bhi|Blo each [128][64] bf16
  __shared__ int rowoff[128];
  const int tid = threadIdx.x;
  const int dir = blockIdx.z;
  const int m0 = blockIdx.x * 128;
  const int n0 = blockIdx.y * 128;
  if (tid < 128) {
    int m = m0 + tid;
    int tt = t0 + (m >> 6);
    int b = m & 63;
    int st = tt;
    if (dir) { st = length[b] - 1 - tt; st = st < 0 ? 0 : (st > 511 ? 511 : st); }
    rowoff[tid] = (b * 512 + st) * 512;
  }
  __syncthreads();
  const unsigned short* wih_d = wih_pl + (size_t)dir * 2097152;
  f32x4 acc[4][4];
#pragma unroll
  for (int i = 0; i < 4; ++i)
#pragma unroll
    for (int j = 0; j < 4; ++j) acc[i][j] = f32x4{0.f, 0.f, 0.f, 0.f};
  const int w = tid >> 6, l = tid & 63;
  const int wm = w & 1, wn = w >> 1;
  for (int ks = 0; ks < 8; ++ks) {
    int k0 = ks * 64;
    __syncthreads();
#pragma unroll
    for (int r = 0; r < 16; ++r) {
      int u = tid + 256 * r;
      int plane = u >> 10;
      int rem = u & 1023;
      int row = rem >> 3, cph = rem & 7;
      int koff = k0 + (cph ^ (row & 7)) * 8;
      const unsigned short* src;
      if (plane < 2) src = xpl + (size_t)plane * 16777216 + rowoff[row] + koff;
      else src = wih_d + (size_t)(plane - 2) * 1048576 + (n0 + row) * 512 + koff;
      *(uint4*)(smem + u * 16) = *(const uint4*)src;
    }
    __syncthreads();
#pragma unroll
    for (int kf = 0; kf < 2; ++kf) {
      bf16x8 ah[4], al[4], bh[4], bl[4];
#pragma unroll
      for (int x = 0; x < 4; ++x) {
        int arow = wm * 64 + x * 16 + (l & 15);
        int ac = (kf * 4 + (l >> 4)) ^ (arow & 7);
        ah[x] = *(const bf16x8*)(smem + arow * 128 + ac * 16);
        al[x] = *(const bf16x8*)(smem + 16384 + arow * 128 + ac * 16);
        int brow = wn * 64 + x * 16 + (l & 15);
        int bc = (kf * 4 + (l >> 4)) ^ (brow & 7);
        bh[x] = *(const bf16x8*)(smem + 32768 + brow * 128 + bc * 16);
        bl[x] = *(const bf16x8*)(smem + 49152 + brow * 128 + bc * 16);
      }
#pragma unroll
      for (int mi = 0; mi < 4; ++mi)
#pragma unroll
        for (int ni = 0; ni < 4; ++ni) {
          acc[mi][ni] = MFMA16(ah[mi], bh[ni], acc[mi][ni]);
          acc[mi][ni] = MFMA16(al[mi], bh[ni], acc[mi][ni]);
          acc[mi][ni] = MFMA16(ah[mi], bl[ni], acc[mi][ni]);
        }
    }
  }
  const float* bias = dir ? bias_b : bias_f;
  float* xpd = xp + (size_t)dir * (size_t)Tc * 131072;
#pragma unroll
  for (int mi = 0; mi < 4; ++mi)
#pragma unroll
    for (int ni = 0; ni < 4; ++ni)
#pragma unroll
      for (int i = 0; i < 4; ++i) {
        int m = m0 + wm * 64 + mi * 16 + (l >> 4) * 4 + i;
        int nn = n0 + wn * 64 + ni * 16 + (l & 15);
        xpd[(size_t)m * 2048 + nn] = acc[mi][ni][i] + bias[nn];
      }
}

// ---------------- persistent recurrence v2 ----------------
// 128 wgs: dir = wg>>6, slice = wg&63 owns 8 hidden units (32 gate-cols).
// 8 waves = 4 mh (16-batch tiles) x 2 nn (16-col tiles), full K per wave.
// LDS: W [2pl][32r x 1040B] | A 4 ping-pong chunk bufs [2pl][64b][64k] | gex.
__global__ __launch_bounds__(512) void lstm_persist(
    const unsigned short* __restrict__ whh_pl,  // [dir][pl][2048][512]
    unsigned* hx,                               // [dir][buf][64][512] u32 packed
    const float* __restrict__ xp,               // [dir][Tc][64][2048]
    const int* __restrict__ length,
    float* __restrict__ Cst, float* __restrict__ Hst,
    unsigned short* __restrict__ outpl,         // [dir][pl][b][t][h]
    unsigned* arrv, int t0, int Tc) {
  __shared__ char smem[140544];
  const int Ab = 66560, Gb = 132096;   // W: [0,66560), A: 4x16384, gex: 8448B
  const int tid = threadIdx.x;
  const int wg = blockIdx.x;
  const int dir = wg >> 6;
  const int j0 = (wg & 63) * 8;
  // ---- stage W once: rows r = gate*8+jj, pad rows to 1040B, 16B-chunk xor --
  const unsigned short* whh_d = whh_pl + (size_t)dir * 2097152;
  for (int u = tid; u < 4096; u += 512) {
    int pl = u >> 11, rem = u & 2047;
    int r = rem >> 6, cph = rem & 63;
    int kc = cph ^ (r & 7);
    int grow = (r >> 3) * 512 + j0 + (r & 7);
    const unsigned short* src = whh_d + (size_t)pl * 1048576 + grow * 512 + kc * 8;
    *(uint4*)(smem + pl * 33280 + r * 1040 + cph * 16) = *(const uint4*)src;
  }
  const int w = tid >> 6, l = tid & 63;
  const int mh = w >> 1;           // 0..3
  const int nn = w & 1;            // 0..1
  const int b = tid >> 3, jj = tid & 7;
  const int j = j0 + jj;
  const int lenb = length[b];
  const size_t sidx = ((size_t)dir * 64 + b) * 512 + j;
  float c_reg, h_reg;
  if (t0 == 0) { c_reg = 0.f; h_reg = 0.f; }
  else { c_reg = Cst[sidx]; h_reg = Hst[sidx]; }
  // staging geometry (thread -> one (b, phys-chunk) granule pair, both planes)
  const int sb = b, scph = jj;
  const int skc = scph ^ (sb & 7);
  float* gex = (float*)(smem + Gb);  // [64][33] f32
  const int arow = 16 * mh + (l & 15);
  const int rcol = 16 * nn + (l & 15);
  const int crow0 = 16 * mh + (l >> 4) * 4;

  for (int tl = 0; tl < Tc; ++tl) {
    const int t = t0 + tl;
    const int cur = t & 1;
    const unsigned* hcur = hx + (size_t)(dir * 2 + cur) * 32768;
    // ---- prefetch xp (independent of h) ----
    const float* xq = xp + ((size_t)dir * Tc + tl) * 131072 + b * 2048 + j;
    float x0 = xq[0], x1 = xq[512], x2 = xq[1024], x3 = xq[1536];
    // ---- load all packed h (relaxed agent, IF$-coherent) ----
    unsigned long long pk[32];
#pragma unroll
    for (int ci = 0; ci < 8; ++ci) {
      const unsigned long long* src =
          (const unsigned long long*)(hcur + sb * 512 + ci * 64 + skc * 8);
#pragma unroll
      for (int p = 0; p < 4; ++p)
        pk[ci * 4 + p] =
            __hip_atomic_load(src + p, __ATOMIC_RELAXED, __HIP_MEMORY_SCOPE_AGENT);
    }
#define STAGE(ci)                                                            \
  {                                                                          \
    char* dstb = smem + Ab + ((ci) & 3) * 16384;                             \
    unsigned long long q0 = pk[(ci) * 4], q1 = pk[(ci) * 4 + 1];             \
    unsigned long long q2 = pk[(ci) * 4 + 2], q3 = pk[(ci) * 4 + 3];         \
    uint4 vh, vl;                                                            \
    vh.x = (unsigned)(q0 & 0xffffu) | ((unsigned)(q0 >> 32) << 16);          \
    vh.y = (unsigned)(q1 & 0xffffu) | ((unsigned)(q1 >> 32) << 16);          \
    vh.z = (unsigned)(q2 & 0xffffu) | ((unsigned)(q2 >> 32) << 16);          \
    vh.w = (unsigned)(q3 & 0xffffu) | ((unsigned)(q3 >> 32) << 16);          \
    vl.x = (unsigned)((q0 >> 16) & 0xffffu) | ((unsigned)(q0 >> 48) << 16);  \
    vl.y = (unsigned)((q1 >> 16) & 0xffffu) | ((unsigned)(q1 >> 48) << 16);  \
    vl.z = (unsigned)((q2 >> 16) & 0xffffu) | ((unsigned)(q2 >> 48) << 16);  \
    vl.w = (unsigned)((q3 >> 16) & 0xffffu) | ((unsigned)(q3 >> 48) << 16);  \
    *(uint4*)(dstb + sb * 128 + scph * 16) = vh;                             \
    *(uint4*)(dstb + 8192 + sb * 128 + scph * 16) = vl;                      \
  }
#define MM(ci, a0, a1)                                                       \
  {                                                                          \
    const char* base = smem + Ab + ((ci) & 3) * 16384;                       \
    _Pragma("unroll")                                                        \
    for (int kc = 0; kc < 2; ++kc) {                                         \
      int kloc = kc * 4 + (l >> 4);                                          \
      int aph = kloc ^ (arow & 7);                                           \
      bf16x8 ahv = *(const bf16x8*)(base + arow * 128 + aph * 16);           \
      bf16x8 alv = *(const bf16x8*)(base + 8192 + arow * 128 + aph * 16);    \
      int kglob = (ci) * 8 + kloc;                                           \
      int bph = kglob ^ (rcol & 7);                                          \
      bf16x8 bhv = *(const bf16x8*)(smem + rcol * 1040 + bph * 16);          \
      bf16x8 blv = *(const bf16x8*)(smem + 33280 + rcol * 1040 + bph * 16);  \
      f32x4& ac = kc ? (a1) : (a0);                                          \
      ac = MFMA16(ahv, bhv, ac);                                             \
      ac = MFMA16(alv, bhv, ac);                                             \
      ac = MFMA16(ahv, blv, ac);                                             \
    }                                                                        \
  }
    f32x4 a0 = f32x4{0.f, 0.f, 0.f, 0.f}, a1 = f32x4{0.f, 0.f, 0.f, 0.f};
    STAGE(0); STAGE(1);
    __syncthreads();
#pragma unroll
    for (int ii = 0; ii < 4; ++ii) {
      if (ii < 3) { STAGE(2 * ii + 2); STAGE(2 * ii + 3); }
      MM(2 * ii, a0, a1);
      MM(2 * ii + 1, a0, a1);
      __syncthreads();
    }
    // ---- gate-col exchange (padded rows, conflict-free-ish) ----
#pragma unroll
    for (int i = 0; i < 4; ++i)
      gex[(crow0 + i) * 33 + rcol] = a0[i] + a1[i];
    __syncthreads();
    {
      float g0 = gex[b * 33 + jj] + x0;
      float g1 = gex[b * 33 + 8 + jj] + x1;
      float g2 = gex[b * 33 + 16 + jj] + x2;
      float g3 = gex[b * 33 + 24 + jj] + x3;
      float ig = 1.f / (1.f + expf(-g0));
      float fg = 1.f / (1.f + expf(-g1));
      float gg = tanhf(g2);
      float og = 1.f / (1.f + expf(-g3));
      float cn = fg * c_reg + ig * gg;
      float hn = og * tanhf(cn);
      bool m = (t < lenb);
      c_reg = m ? cn : c_reg;
      h_reg = m ? hn : h_reg;
      unsigned short hi = f2bf(h_reg);
      unsigned short lo = f2bf(h_reg - bf2f(hi));
      unsigned* hnxt = hx + (size_t)(dir * 2 + (cur ^ 1)) * 32768;
      __hip_atomic_store(&hnxt[b * 512 + j], (unsigned)hi | ((unsigned)lo << 16),
                         __ATOMIC_RELAXED, __HIP_MEMORY_SCOPE_AGENT);
      if (dir == 0) {
        size_t rb = ((size_t)b * 512 + t) * 512 + j;
        outpl[rb] = m ? hi : (unsigned short)0;
        outpl[16777216 + rb] = m ? lo : (unsigned short)0;
      } else if (m) {
        int tp = lenb - 1 - t;
        size_t rb = ((size_t)b * 512 + tp) * 512 + j;
        outpl[(size_t)2 * 16777216 + rb] = hi;
        outpl[(size_t)3 * 16777216 + rb] = lo;
      }
    }
    // ---- per-direction arrival-array barrier (relaxed only) ----
    if (tl != Tc - 1) {
      __syncthreads();  // compiler drains vmcnt(0): h-stores ack'd at IF$
      if (w == 0) {
        unsigned e = (unsigned)(tl + 1);
        if (l == 0)
          __hip_atomic_store(&arrv[wg], e, __ATOMIC_RELAXED, __HIP_MEMORY_SCOPE_AGENT);
        const unsigned* grp = arrv + dir * 64;
        while (true) {
          unsigned v = __hip_atomic_load(&grp[l], __ATOMIC_RELAXED,
                                         __HIP_MEMORY_SCOPE_AGENT);
          if (__all(v >= e)) break;
          __builtin_amdgcn_s_sleep(1);
        }
      }
      __syncthreads();
    }
  }
  Cst[sidx] = c_reg;
  Hst[sidx] = h_reg;
#undef STAGE
#undef MM
}

// ---------------- emissions (unchanged) ----------------
__global__ __launch_bounds__(256) void emis_kernel(
    const unsigned short* __restrict__ outpl, const float* __restrict__ Wout,
    const float* __restrict__ bout, float* __restrict__ emis) {
  __shared__ float red[64][25][4];
  int tid = threadIdx.x;
  int p = tid >> 6, rr = tid & 63;
  int r = blockIdx.x * 64 + rr;
  int b = r >> 9, t = r & 511;
  int dir = p >> 1;
  int jq = (p & 1) * 256;
  const unsigned short* hp = outpl + (size_t)(dir * 2) * 16777216 + ((size_t)b * 512 + t) * 512 + jq;
  const unsigned short* lp = outpl + (size_t)(dir * 2 + 1) * 16777216 + ((size_t)b * 512 + t) * 512 + jq;
  float acc[24];
#pragma unroll
  for (int i = 0; i < 24; ++i) acc[i] = 0.f;
  for (int kc = 0; kc < 32; ++kc) {
    uint4 vh = *(const uint4*)(hp + kc * 8);
    uint4 vl = *(const uint4*)(lp + kc * 8);
    unsigned uh[4] = {vh.x, vh.y, vh.z, vh.w};
    unsigned ul[4] = {vl.x, vl.y, vl.z, vl.w};
    float f[8];
#pragma unroll
    for (int z = 0; z < 4; ++z) {
      f[2 * z] = bf2f((unsigned short)(uh[z] & 0xffff)) + bf2f((unsigned short)(ul[z] & 0xffff));
      f[2 * z + 1] = bf2f((unsigned short)(uh[z] >> 16)) + bf2f((unsigned short)(ul[z] >> 16));
    }
    const float* wbase = Wout + dir * 512 + jq + kc * 8;
#pragma unroll
    for (int nn = 0; nn < 24; ++nn) {
      const float* wr = wbase + nn * 1024;
      float4 w0 = *(const float4*)(wr);
      float4 w1 = *(const float4*)(wr + 4);
      acc[nn] += f[0] * w0.x + f[1] * w0.y + f[2] * w0.z + f[3] * w0.w +
                 f[4] * w1.x + f[5] * w1.y + f[6] * w1.z + f[7] * w1.w;
    }
  }
#pragma unroll
  for (int nn = 0; nn < 24; ++nn) red[rr][nn][p] = acc[nn];
  __syncthreads();
#pragma unroll
  for (int oi = 0; oi < 6; ++oi) {
    int idx = tid + 256 * oi;
    int rr2 = idx / 24, n2 = idx % 24;
    float v = red[rr2][n2][0] + red[rr2][n2][1] + red[rr2][n2][2] + red[rr2][n2][3] + bout[n2];
    emis[((size_t)blockIdx.x * 64 + rr2) * 24 + n2] = v;
  }
}

// ---------------- Viterbi v2: LDS-staged emissions, reg transitions --------
__global__ __launch_bounds__(64) void viterbi_kernel(
    const float* __restrict__ emis, const int* __restrict__ length,
    const float* __restrict__ trans, float* __restrict__ out) {
  __shared__ float eb[12288];        // 48 KB: this batch's emission row
  __shared__ float tr[576];
  __shared__ unsigned char bp[512 * 24];
  __shared__ unsigned char seq[512];
  int b = blockIdx.x, l = threadIdx.x;
  const float* ebg = emis + (size_t)b * 12288;
  for (int i = l * 4; i < 12288; i += 256)
    *(float4*)(eb + i) = *(const float4*)(ebg + i);
  for (int i = l; i < 576; i += 64) tr[i] = trans[i];
  __syncthreads();
  int lc = (l < 24) ? l : 0;
  float tcol[24];
#pragma unroll
  for (int p = 0; p < 24; ++p) tcol[p] = tr[p * 24 + lc];
  int len = length[b];
  float alpha = (l < 24) ? eb[lc] + tr[22 * 24 + lc] : -3e38f;
  for (int t = 1; t < 512; ++t) {
    float mx = -3e38f;
    int arg = 0;
#pragma unroll
    for (int p = 0; p < 24; ++p) {
      float v = __shfl(alpha, p) + tcol[p];
      if (v > mx) { mx = v; arg = p; }  // strict > keeps first max
    }
    if (l < 24) {
      bp[t * 24 + l] = (unsigned char)arg;
      if (t < len) alpha = mx + eb[t * 24 + l];
    }
  }
  float fin = (l < 24) ? alpha + tr[lc * 24 + 23] : -3e38f;
  float best = -3e38f;
  int cur = 0;
  for (int p = 0; p < 24; ++p) {
    float v = __shfl(fin, p);
    if (v > best) { best = v; cur = p; }
  }
  int last = len - 1;
  if (l == 0) {
    out[b] = best;
    int c = cur;
    for (int t = 511; t >= 0; --t) {
      seq[t] = (unsigned char)c;
      if (t >= 1 && t <= last) c = bp[t * 24 + c];
    }
  }
  __syncthreads();
  for (int i = l; i < 512; i += 64) out[64 + b * 512 + i] = (float)seq[i];
}

// ---------------- host ----------------
extern "C" void kernel_launch(void* const* d_in, const int* in_sizes, int n_in,
                              void* d_out, int out_size, void* d_ws, size_t ws_size,
                              hipStream_t stream) {
  const float* X = (const float*)d_in[0];
  const int* length = (const int*)d_in[2];
  const float* Wih_f = (const float*)d_in[3];
  const float* Whh_f = (const float*)d_in[4];
  const float* b_f = (const float*)d_in[5];
  const float* Wih_b = (const float*)d_in[6];
  const float* Whh_b = (const float*)d_in[7];
  const float* b_b = (const float*)d_in[8];
  const float* Wout = (const float*)d_in[9];
  const float* bout = (const float*)d_in[10];
  const float* trans = (const float*)d_in[11];

  char* ws = (char*)d_ws;
  unsigned short* whh_pl = (unsigned short*)(ws + O_WHH);
  unsigned short* wih_pl = (unsigned short*)(ws + O_WIH);
  unsigned short* xspl = (unsigned short*)(ws + O_XSPL);
  unsigned short* outpl = (unsigned short*)(ws + O_OUTPL);
  unsigned* hx = (unsigned*)(ws + O_HBUF);
  float* Hbuf = (float*)(ws + O_HF32);
  float* Cbuf = (float*)(ws + O_CF32);
  float* emis = (float*)(ws + O_EMIS);
  unsigned* bar = (unsigned*)(ws + O_BAR);
  float* xp = (float*)(ws + O_XP);

  int Tc = 2;
  const int cands[9] = {512, 256, 128, 64, 32, 16, 8, 4, 2};
  for (int i = 0; i < 9; ++i) {
    if (O_XP + (size_t)cands[i] * 1048576 <= ws_size) { Tc = cands[i]; break; }
  }
  int nch = T_ / Tc;

  hipMemsetAsync(ws + O_OUTPL, 0, SZ_OUTPL, stream);
  hipMemsetAsync(ws + O_HBUF, 0, SZ_HBUF, stream);

  split_kernel<<<2048, 256, 0, stream>>>(Whh_f, whh_pl, whh_pl + 1048576, 1048576);
  split_kernel<<<2048, 256, 0, stream>>>(Whh_b, whh_pl + 2097152, whh_pl + 3145728, 1048576);
  split_kernel<<<2048, 256, 0, stream>>>(Wih_f, wih_pl, wih_pl + 1048576, 1048576);
  split_kernel<<<2048, 256, 0, stream>>>(Wih_b, wih_pl + 2097152, wih_pl + 3145728, 1048576);
  split_kernel<<<8192, 256, 0, stream>>>(X, xspl, xspl + 16777216, 16777216);

  for (int ch = 0; ch < nch; ++ch) {
    int t0 = ch * Tc;
    xp_gemm<<<dim3(Tc * 64 / 128, 16, 2), 256, 0, stream>>>(
        xspl, wih_pl, b_f, b_b, length, xp, t0, Tc);
    hipMemsetAsync(bar, 0, 512, stream);
    lstm_persist<<<128, 512, 0, stream>>>(whh_pl, hx, xp, length, Cbuf, Hbuf,
                                          outpl, bar, t0, Tc);
  }
  emis_kernel<<<512, 256, 0, stream>>>(outpl, Wout, bout, emis);
  viterbi_kernel<<<64, 64, 0, stream>>>(emis, length, trans, (float*)d_out);
}

// Round 6
// 4326.012 us; speedup vs baseline: 1.5007x; 1.5007x over previous
//
#include <hip/hip_runtime.h>

// ============================================================================
// BiLSTM + CRF Viterbi.  Round 6: single-bf16 numerics (threshold analysis:
// tags can't fail, scores need <=23 abs -> bf16 is plenty), register-resident
// A-operand, non-temporal wide h-loads (no atomics on the load side), dual-dir
// workgroups with phase-interleaved latency hiding, Tc=128.
// ============================================================================

#define B_ 64
#define T_ 512
#define NT_ 24

typedef __attribute__((ext_vector_type(8))) short bf16x8;
typedef __attribute__((ext_vector_type(4))) float f32x4;
typedef __attribute__((ext_vector_type(4))) unsigned int u32x4;

#define MFMA16(a, b, c) __builtin_amdgcn_mfma_f32_16x16x32_bf16(a, b, c, 0, 0, 0)

__device__ __forceinline__ unsigned short f2bf(float x) {
  unsigned u = __float_as_uint(x);
  u += 0x7FFFu + ((u >> 16) & 1u);  // round-to-nearest-even
  return (unsigned short)(u >> 16);
}
__device__ __forceinline__ float bf2f(unsigned short h) {
  return __uint_as_float(((unsigned)h) << 16);
}

// ---------------- ws layout (bytes) ----------------
#define O_WHHB  ((size_t)0)                     // [dir][2048][512] u16 = 4MB
#define O_WIHB  ((size_t)4194304)               // [dir][2048][512] u16 = 4MB
#define O_XB    ((size_t)8388608)               // [64][512][512] u16 = 32MB
#define O_OUT   ((size_t)41943040)              // [dir][b][t][512] u16 = 64MB
#define SZ_OUT  ((size_t)67108864)
#define O_HX    ((size_t)109051904)             // [dir][buf][64][256] u32 = 256KB
#define SZ_HX   ((size_t)262144)
#define O_HF    ((size_t)109314048)             // [dir][64][512] f32
#define O_CF    ((size_t)109576192)
#define O_EMIS  ((size_t)109838336)             // [64][512][24] f32 = 3MB
#define O_BAR   ((size_t)112984064)             // 512B arrival arrays
#define O_XP    ((size_t)112984576)             // [2][Tc][64][2048] f32 = Tc MiB

// ---------------- fp32 -> bf16 cast ----------------
__global__ void cast_bf(const float* __restrict__ src,
                        unsigned short* __restrict__ dst, int n) {
  int i = (blockIdx.x * blockDim.x + threadIdx.x) * 4;
  int stride = gridDim.x * blockDim.x * 4;
  for (; i < n; i += stride) {
    float4 v = *(const float4*)(src + i);
    ushort4 o;
    o.x = f2bf(v.x); o.y = f2bf(v.y); o.z = f2bf(v.z); o.w = f2bf(v.w);
    *(ushort4*)(dst + i) = o;
  }
}

// ---------------- xp GEMM (single bf16 product) ----------------
__global__ __launch_bounds__(256) void xp_gemm(
    const unsigned short* __restrict__ xb,      // [64][512][512] bf16
    const unsigned short* __restrict__ wih,     // [dir][2048][512] bf16
    const float* __restrict__ bias_f, const float* __restrict__ bias_b,
    const int* __restrict__ length,
    float* __restrict__ xp, int t0, int Tc) {
  __shared__ char smem[32768];   // A[128][64] | B[128][64] bf16
  __shared__ int rowoff[128];
  const int tid = threadIdx.x;
  const int dir = blockIdx.z;
  const int m0 = blockIdx.x * 128;
  const int n0 = blockIdx.y * 128;
  if (tid < 128) {
    int m = m0 + tid;
    int tt = t0 + (m >> 6);
    int b = m & 63;
    int st = tt;
    if (dir) { st = length[b] - 1 - tt; st = st < 0 ? 0 : (st > 511 ? 511 : st); }
    rowoff[tid] = (b * 512 + st) * 512;
  }
  __syncthreads();
  const unsigned short* wih_d = wih + (size_t)dir * 1048576;
  f32x4 acc[4][4];
#pragma unroll
  for (int i = 0; i < 4; ++i)
#pragma unroll
    for (int j = 0; j < 4; ++j) acc[i][j] = f32x4{0.f, 0.f, 0.f, 0.f};
  const int w = tid >> 6, l = tid & 63;
  const int wm = w & 1, wn = w >> 1;
  for (int ks = 0; ks < 8; ++ks) {
    int k0 = ks * 64;
    __syncthreads();
#pragma unroll
    for (int r = 0; r < 8; ++r) {
      int u = tid + 256 * r;
      int plane = u >> 10;
      int rem = u & 1023;
      int row = rem >> 3, cph = rem & 7;
      int koff = k0 + (cph ^ (row & 7)) * 8;
      const unsigned short* src;
      if (plane == 0) src = xb + rowoff[row] + koff;
      else src = wih_d + (n0 + row) * 512 + koff;
      *(uint4*)(smem + u * 16) = *(const uint4*)src;
    }
    __syncthreads();
#pragma unroll
    for (int kf = 0; kf < 2; ++kf) {
      bf16x8 ah[4], bh[4];
#pragma unroll
      for (int x = 0; x < 4; ++x) {
        int arow = wm * 64 + x * 16 + (l & 15);
        int ac = (kf * 4 + (l >> 4)) ^ (arow & 7);
        ah[x] = *(const bf16x8*)(smem + arow * 128 + ac * 16);
        int brow = wn * 64 + x * 16 + (l & 15);
        int bc = (kf * 4 + (l >> 4)) ^ (brow & 7);
        bh[x] = *(const bf16x8*)(smem + 16384 + brow * 128 + bc * 16);
      }
#pragma unroll
      for (int mi = 0; mi < 4; ++mi)
#pragma unroll
        for (int ni = 0; ni < 4; ++ni)
          acc[mi][ni] = MFMA16(ah[mi], bh[ni], acc[mi][ni]);
    }
  }
  const float* bias = dir ? bias_b : bias_f;
  float* xpd = xp + (size_t)dir * (size_t)Tc * 131072;
#pragma unroll
  for (int mi = 0; mi < 4; ++mi)
#pragma unroll
    for (int ni = 0; ni < 4; ++ni)
#pragma unroll
      for (int i = 0; i < 4; ++i) {
        int m = m0 + wm * 64 + mi * 16 + (l >> 4) * 4 + i;
        int nn = n0 + wn * 64 + ni * 16 + (l & 15);
        xpd[(size_t)m * 2048 + nn] = acc[mi][ni][i] + bias[nn];
      }
}

// ---------------- persistent recurrence v3 ----------------
// 64 wgs, each owns 8 hidden units for BOTH directions.  8 waves =
// 4 mh (16-batch tiles) x 2 kh (256-k halves); A (=h) loaded straight to
// registers in MFMA fragment layout via NON-TEMPORAL 16B loads (no-allocate
// -> never a stale L2 hit; producers store via relaxed agent atomics =
// write-through, proven in R4/R5).  Phase A (dir0) / phase B (dir1)
// interleaved so each dir's barrier latency hides under the other's compute.
__global__ __launch_bounds__(512) void lstm_persist(
    const unsigned short* __restrict__ whh,     // [dir][2048][512] bf16
    unsigned* hx,                               // [dir][buf][64][256] u32 (j-pairs)
    const float* __restrict__ xp,               // [dir][Tc][64][2048]
    const int* __restrict__ length,
    float* __restrict__ Cst, float* __restrict__ Hst,
    unsigned short* __restrict__ outbf,         // [dir][b][t][512] bf16
    unsigned* arrv, int t0, int Tc) {
  __shared__ char smem[100352];  // W[2dir][32r][1024B] | gex[2dir][2kh][64][34]f32
  const int tid = threadIdx.x;
  const int wg = blockIdx.x;     // 0..63
  const int j0 = wg * 8;
  // ---- stage W once (both dirs), 1024B rows + granule-XOR (R4-proven) ----
  for (int u = tid; u < 4096; u += 512) {
    int dir = u >> 11, rem = u & 2047;
    int r = rem >> 6, cph = rem & 63;
    int klog = cph ^ (r & 7);
    int grow = (r >> 3) * 512 + j0 + (r & 7);   // gate*512 + j
    const unsigned short* src = whh + (size_t)dir * 1048576 + grow * 512 + klog * 8;
    *(uint4*)(smem + dir * 32768 + r * 1024 + cph * 16) = *(const uint4*)src;
  }
  const int l = tid & 63;
  const int w = tid >> 6;
  const int mh = w >> 1, kh = w & 1;
  const int b = tid >> 3, jj = tid & 7;
  const int j = j0 + jj;
  const int lenb = length[b];
  const int rowA = 16 * mh + (l & 15);
  const int q = l >> 4;
  const int r0 = l & 15, r1 = 16 + (l & 15);
  float* gex = (float*)(smem + 65536);  // [dir][kh][64][34]
  float c0, h0, c1, h1;
  const size_t s0 = (size_t)b * 512 + j;
  const size_t s1 = (size_t)(64 + b) * 512 + j;
  if (t0 == 0) { c0 = h0 = c1 = h1 = 0.f; }
  else { c0 = Cst[s0]; h0 = Hst[s0]; c1 = Cst[s1]; h1 = Hst[s1]; }
  __syncthreads();  // W staged

  for (int tl = 0; tl < Tc; ++tl) {
    const int t = t0 + tl;
    const int cur = t & 1;
    // xp prefetch (both dirs; consumed after MFMA+sync -> latency hidden)
    const float* xq0 = xp + (size_t)tl * 131072 + b * 2048 + j;
    const float* xq1 = xq0 + (size_t)Tc * 131072;
    float xA0 = xq0[0], xA1 = xq0[512], xA2 = xq0[1024], xA3 = xq0[1536];
    float xB0 = xq1[0], xB1 = xq1[512], xB2 = xq1[1024], xB3 = xq1[1536];
    // ---- poll dir0 ready ----
    if (tl > 0) {
      while (true) {
        unsigned v = __hip_atomic_load(&arrv[l], __ATOMIC_RELAXED,
                                       __HIP_MEMORY_SCOPE_AGENT);
        if (__all((int)(v >= (unsigned)tl))) break;
        __builtin_amdgcn_s_sleep(1);
      }
    }
    asm volatile("" ::: "memory");
    // ---- load A frags dir0 (nt 16B, fragment layout) ----
    const char* hA = (const char*)hx + (size_t)cur * 65536;
    u32x4 fA[8];
#pragma unroll
    for (int kc = 0; kc < 8; ++kc)
      fA[kc] = __builtin_nontemporal_load(
          (u32x4*)(hA + rowA * 1024 + (kh * 8 + kc) * 64 + q * 16));
    // ---- MFMA dir0 ----
    f32x4 aA0 = f32x4{0.f, 0.f, 0.f, 0.f}, aA1 = f32x4{0.f, 0.f, 0.f, 0.f};
#pragma unroll
    for (int kc = 0; kc < 8; ++kc) {
      bf16x8 av = __builtin_bit_cast(bf16x8, fA[kc]);
      int kg = (kh * 8 + kc) * 4 + q;
      bf16x8 b0 = *(const bf16x8*)(smem + r0 * 1024 + (kg ^ (r0 & 7)) * 16);
      bf16x8 b1 = *(const bf16x8*)(smem + r1 * 1024 + (kg ^ (r1 & 7)) * 16);
      aA0 = MFMA16(av, b0, aA0);
      aA1 = MFMA16(av, b1, aA1);
    }
    // ---- poll dir1 + load A frags dir1 (early: hides under phase-A tail) --
    if (tl > 0) {
      while (true) {
        unsigned v = __hip_atomic_load(&arrv[64 + l], __ATOMIC_RELAXED,
                                       __HIP_MEMORY_SCOPE_AGENT);
        if (__all((int)(v >= (unsigned)tl))) break;
        __builtin_amdgcn_s_sleep(1);
      }
    }
    asm volatile("" ::: "memory");
    const char* hB = (const char*)hx + (size_t)(2 + cur) * 65536;
    u32x4 fB[8];
#pragma unroll
    for (int kc = 0; kc < 8; ++kc)
      fB[kc] = __builtin_nontemporal_load(
          (u32x4*)(hB + rowA * 1024 + (kh * 8 + kc) * 64 + q * 16));
    // ---- gex write dir0 ----
    {
      float* gA = gex + kh * 2176;
#pragma unroll
      for (int i = 0; i < 4; ++i) {
        gA[(16 * mh + 4 * q + i) * 34 + r0] = aA0[i];
        gA[(16 * mh + 4 * q + i) * 34 + r1] = aA1[i];
      }
    }
    __syncthreads();  // S1
    // ---- gate dir0 ----
    {
      float g0 = gex[b * 34 + jj]      + gex[2176 + b * 34 + jj]      + xA0;
      float g1 = gex[b * 34 + 8 + jj]  + gex[2176 + b * 34 + 8 + jj]  + xA1;
      float g2 = gex[b * 34 + 16 + jj] + gex[2176 + b * 34 + 16 + jj] + xA2;
      float g3 = gex[b * 34 + 24 + jj] + gex[2176 + b * 34 + 24 + jj] + xA3;
      float ig = 1.f / (1.f + expf(-g0));
      float fg = 1.f / (1.f + expf(-g1));
      float gg = tanhf(g2);
      float og = 1.f / (1.f + expf(-g3));
      float cn = fg * c0 + ig * gg;
      float hn = og * tanhf(cn);
      bool m = (t < lenb);
      c0 = m ? cn : c0;
      h0 = m ? hn : h0;
      unsigned short hb = f2bf(h0);
      float hnx = __shfl(h0, (l + 1) & 63);
      if (!(jj & 1)) {
        unsigned hp = (unsigned)hb | ((unsigned)f2bf(hnx) << 16);
        unsigned* dst = hx + (size_t)(cur ^ 1) * 16384 + b * 256 + (j >> 1);
        __hip_atomic_store(dst, hp, __ATOMIC_RELAXED, __HIP_MEMORY_SCOPE_AGENT);
      }
      outbf[((size_t)b * 512 + t) * 512 + j] = m ? hb : (unsigned short)0;
    }
    __syncthreads();  // S2 (drains h-stores wg-wide before arrival)
    if (tid == 0 && tl + 1 < Tc)
      __hip_atomic_store(&arrv[wg], (unsigned)(tl + 1), __ATOMIC_RELAXED,
                         __HIP_MEMORY_SCOPE_AGENT);
    // ---- MFMA dir1 ----
    f32x4 aB0 = f32x4{0.f, 0.f, 0.f, 0.f}, aB1 = f32x4{0.f, 0.f, 0.f, 0.f};
#pragma unroll
    for (int kc = 0; kc < 8; ++kc) {
      bf16x8 av = __builtin_bit_cast(bf16x8, fB[kc]);
      int kg = (kh * 8 + kc) * 4 + q;
      bf16x8 b0 = *(const bf16x8*)(smem + 32768 + r0 * 1024 + (kg ^ (r0 & 7)) * 16);
      bf16x8 b1 = *(const bf16x8*)(smem + 32768 + r1 * 1024 + (kg ^ (r1 & 7)) * 16);
      aB0 = MFMA16(av, b0, aB0);
      aB1 = MFMA16(av, b1, aB1);
    }
    {
      float* gB = gex + 4352 + kh * 2176;
#pragma unroll
      for (int i = 0; i < 4; ++i) {
        gB[(16 * mh + 4 * q + i) * 34 + r0] = aB0[i];
        gB[(16 * mh + 4 * q + i) * 34 + r1] = aB1[i];
      }
    }
    __syncthreads();  // S3
    // ---- gate dir1 ----
    {
      const float* gx = gex + 4352;
      float g0 = gx[b * 34 + jj]      + gx[2176 + b * 34 + jj]      + xB0;
      float g1 = gx[b * 34 + 8 + jj]  + gx[2176 + b * 34 + 8 + jj]  + xB1;
      float g2 = gx[b * 34 + 16 + jj] + gx[2176 + b * 34 + 16 + jj] + xB2;
      float g3 = gx[b * 34 + 24 + jj] + gx[2176 + b * 34 + 24 + jj] + xB3;
      float ig = 1.f / (1.f + expf(-g0));
      float fg = 1.f / (1.f + expf(-g1));
      float gg = tanhf(g2);
      float og = 1.f / (1.f + expf(-g3));
      float cn = fg * c1 + ig * gg;
      float hn = og * tanhf(cn);
      bool m = (t < lenb);
      c1 = m ? cn : c1;
      h1 = m ? hn : h1;
      unsigned short hb = f2bf(h1);
      float hnx = __shfl(h1, (l + 1) & 63);
      if (!(jj & 1)) {
        unsigned hp = (unsigned)hb | ((unsigned)f2bf(hnx) << 16);
        unsigned* dst = hx + (size_t)(2 + (cur ^ 1)) * 16384 + b * 256 + (j >> 1);
        __hip_atomic_store(dst, hp, __ATOMIC_RELAXED, __HIP_MEMORY_SCOPE_AGENT);
      }
      if (m) {
        int tp = lenb - 1 - t;
        outbf[(size_t)16777216 + ((size_t)b * 512 + tp) * 512 + j] = hb;
      }
    }
    __syncthreads();  // S4
    if (tid == 0 && tl + 1 < Tc)
      __hip_atomic_store(&arrv[64 + wg], (unsigned)(tl + 1), __ATOMIC_RELAXED,
                         __HIP_MEMORY_SCOPE_AGENT);
  }
  Cst[s0] = c0; Hst[s0] = h0;
  Cst[s1] = c1; Hst[s1] = h1;
}

// ---------------- emissions (single-plane bf16) ----------------
__global__ __launch_bounds__(256) void emis_kernel(
    const unsigned short* __restrict__ outbf, const float* __restrict__ Wout,
    const float* __restrict__ bout, float* __restrict__ emis) {
  __shared__ float red[64][25][4];
  int tid = threadIdx.x;
  int p = tid >> 6, rr = tid & 63;
  int r = blockIdx.x * 64 + rr;
  int b = r >> 9, t = r & 511;
  int dir = p >> 1;
  int jq = (p & 1) * 256;
  const unsigned short* hp =
      outbf + (size_t)dir * 16777216 + ((size_t)b * 512 + t) * 512 + jq;
  float acc[24];
#pragma unroll
  for (int i = 0; i < 24; ++i) acc[i] = 0.f;
  for (int kc = 0; kc < 32; ++kc) {
    uint4 vh = *(const uint4*)(hp + kc * 8);
    unsigned uh[4] = {vh.x, vh.y, vh.z, vh.w};
    float f[8];
#pragma unroll
    for (int z = 0; z < 4; ++z) {
      f[2 * z] = bf2f((unsigned short)(uh[z] & 0xffff));
      f[2 * z + 1] = bf2f((unsigned short)(uh[z] >> 16));
    }
    const float* wbase = Wout + dir * 512 + jq + kc * 8;
#pragma unroll
    for (int nn = 0; nn < 24; ++nn) {
      const float* wr = wbase + nn * 1024;
      float4 w0 = *(const float4*)(wr);
      float4 w1 = *(const float4*)(wr + 4);
      acc[nn] += f[0] * w0.x + f[1] * w0.y + f[2] * w0.z + f[3] * w0.w +
                 f[4] * w1.x + f[5] * w1.y + f[6] * w1.z + f[7] * w1.w;
    }
  }
#pragma unroll
  for (int nn = 0; nn < 24; ++nn) red[rr][nn][p] = acc[nn];
  __syncthreads();
#pragma unroll
  for (int oi = 0; oi < 6; ++oi) {
    int idx = tid + 256 * oi;
    int rr2 = idx / 24, n2 = idx % 24;
    float v = red[rr2][n2][0] + red[rr2][n2][1] + red[rr2][n2][2] +
              red[rr2][n2][3] + bout[n2];
    emis[((size_t)blockIdx.x * 64 + rr2) * 24 + n2] = v;
  }
}

// ---------------- Viterbi (R5 version) ----------------
__global__ __launch_bounds__(64) void viterbi_kernel(
    const float* __restrict__ emis, const int* __restrict__ length,
    const float* __restrict__ trans, float* __restrict__ out) {
  __shared__ float eb[12288];
  __shared__ float tr[576];
  __shared__ unsigned char bp[512 * 24];
  __shared__ unsigned char seq[512];
  int b = blockIdx.x, l = threadIdx.x;
  const float* ebg = emis + (size_t)b * 12288;
  for (int i = l * 4; i < 12288; i += 256)
    *(float4*)(eb + i) = *(const float4*)(ebg + i);
  for (int i = l; i < 576; i += 64) tr[i] = trans[i];
  __syncthreads();
  int lc = (l < 24) ? l : 0;
  float tcol[24];
#pragma unroll
  for (int p = 0; p < 24; ++p) tcol[p] = tr[p * 24 + lc];
  int len = length[b];
  float alpha = (l < 24) ? eb[lc] + tr[22 * 24 + lc] : -3e38f;
  for (int t = 1; t < 512; ++t) {
    float mx = -3e38f;
    int arg = 0;
#pragma unroll
    for (int p = 0; p < 24; ++p) {
      float v = __shfl(alpha, p) + tcol[p];
      if (v > mx) { mx = v; arg = p; }
    }
    if (l < 24) {
      bp[t * 24 + l] = (unsigned char)arg;
      if (t < len) alpha = mx + eb[t * 24 + l];
    }
  }
  float fin = (l < 24) ? alpha + tr[lc * 24 + 23] : -3e38f;
  float best = -3e38f;
  int cur = 0;
  for (int p = 0; p < 24; ++p) {
    float v = __shfl(fin, p);
    if (v > best) { best = v; cur = p; }
  }
  int last = len - 1;
  if (l == 0) {
    out[b] = best;
    int c = cur;
    for (int t = 511; t >= 0; --t) {
      seq[t] = (unsigned char)c;
      if (t >= 1 && t <= last) c = bp[t * 24 + c];
    }
  }
  __syncthreads();
  for (int i = l; i < 512; i += 64) out[64 + b * 512 + i] = (float)seq[i];
}

// ---------------- host ----------------
extern "C" void kernel_launch(void* const* d_in, const int* in_sizes, int n_in,
                              void* d_out, int out_size, void* d_ws, size_t ws_size,
                              hipStream_t stream) {
  const float* X = (const float*)d_in[0];
  const int* length = (const int*)d_in[2];
  const float* Wih_f = (const float*)d_in[3];
  const float* Whh_f = (const float*)d_in[4];
  const float* b_f = (const float*)d_in[5];
  const float* Wih_b = (const float*)d_in[6];
  const float* Whh_b = (const float*)d_in[7];
  const float* b_b = (const float*)d_in[8];
  const float* Wout = (const float*)d_in[9];
  const float* bout = (const float*)d_in[10];
  const float* trans = (const float*)d_in[11];

  char* ws = (char*)d_ws;
  unsigned short* whh_bf = (unsigned short*)(ws + O_WHHB);
  unsigned short* wih_bf = (unsigned short*)(ws + O_WIHB);
  unsigned short* xb = (unsigned short*)(ws + O_XB);
  unsigned short* outbf = (unsigned short*)(ws + O_OUT);
  unsigned* hx = (unsigned*)(ws + O_HX);
  float* Hbuf = (float*)(ws + O_HF);
  float* Cbuf = (float*)(ws + O_CF);
  float* emis = (float*)(ws + O_EMIS);
  unsigned* bar = (unsigned*)(ws + O_BAR);
  float* xp = (float*)(ws + O_XP);

  int Tc = 2;
  const int cands[9] = {512, 256, 128, 64, 32, 16, 8, 4, 2};
  for (int i = 0; i < 9; ++i) {
    if (O_XP + (size_t)cands[i] * 1048576 <= ws_size) { Tc = cands[i]; break; }
  }
  int nch = T_ / Tc;

  hipMemsetAsync(ws + O_OUT, 0, SZ_OUT, stream);
  hipMemsetAsync(ws + O_HX, 0, SZ_HX, stream);

  cast_bf<<<1024, 256, 0, stream>>>(Whh_f, whh_bf, 1048576);
  cast_bf<<<1024, 256, 0, stream>>>(Whh_b, whh_bf + 1048576, 1048576);
  cast_bf<<<1024, 256, 0, stream>>>(Wih_f, wih_bf, 1048576);
  cast_bf<<<1024, 256, 0, stream>>>(Wih_b, wih_bf + 1048576, 1048576);
  cast_bf<<<4096, 256, 0, stream>>>(X, xb, 16777216);

  for (int ch = 0; ch < nch; ++ch) {
    int t0 = ch * Tc;
    xp_gemm<<<dim3(Tc * 64 / 128, 16, 2), 256, 0, stream>>>(
        xb, wih_bf, b_f, b_b, length, xp, t0, Tc);
    hipMemsetAsync(bar, 0, 512, stream);
    lstm_persist<<<64, 512, 0, stream>>>(whh_bf, hx, xp, length, Cbuf, Hbuf,
                                         outbf, bar, t0, Tc);
  }
  emis_kernel<<<512, 256, 0, stream>>>(outbf, Wout, bout, emis);
  viterbi_kernel<<<64, 64, 0, stream>>>(emis, length, trans, (float*)d_out);
}